// Round 11
// baseline (14.345 us; speedup 1.0000x reference)
//
#include <hip/hip_runtime.h>
#include <math.h>

// HybridSymmetricLoss: B=8192, P=4, M=12, 24 perms.
// pairS[p][q] = sum_{i,j} (y[p] ? log a[q] : log1p(-a[q]))  (negated BCE)
// best perm = argmax_sigma sum_p pairS[p][sigma(p)]; category BCE via sigma.
// kernel1: 1 batch per 64-lane wave (r10 wave body, byte-identical), now
//   8 waves per 512-thread block, 1024 blocks (4 blocks/CU = 32 waves/CU,
//   full occupancy). Per-block partial -> bsums[1024].
// kernel2: ONE 64-lane wave, no LDS, no barriers: 4 float4 loads/lane,
//   fp64 butterfly, lane-0 store. Fixed order -> deterministic.

#define LOG2_CLIP (-144.26950408889634f)   // -100 / ln(2)
#define LN2F      (0.6931471805599453f)

typedef int v2i __attribute__((ext_vector_type(2)));

// lane<32: a[lane]+a[lane^32] ; lane>=32: b[lane]+b[lane^32]
__device__ __forceinline__ float pl32_add(float a, float b) {
    v2i r = __builtin_amdgcn_permlane32_swap(__float_as_int(a),
                                             __float_as_int(b), false, false);
    return __int_as_float(r[0]) + __int_as_float(r[1]);
}
// (lane&16)==0: a[lane]+a[lane^16] ; else: b[lane]+b[lane^16]
__device__ __forceinline__ float pl16_add(float a, float b) {
    v2i r = __builtin_amdgcn_permlane16_swap(__float_as_int(a),
                                             __float_as_int(b), false, false);
    return __int_as_float(r[0]) + __int_as_float(r[1]);
}
// DPP quad_perm xor-1 / xor-2 (pure VALU, no LDS pipe)
__device__ __forceinline__ float dpp_x1(float x) {
    return __int_as_float(__builtin_amdgcn_update_dpp(
        0, __float_as_int(x), 0xB1, 0xF, 0xF, false));
}
__device__ __forceinline__ float dpp_x2(float x) {
    return __int_as_float(__builtin_amdgcn_update_dpp(
        0, __float_as_int(x), 0x4E, 0xF, 0xF, false));
}

// perm table, lexicographic. byte p = 16*p + 4*sigma(p) = x-gather lane;
// byte>>2 = 4*p + sigma(p) = catv lane.
#define PK(a,b,c,d) ((unsigned)((4u*(a)) | ((16u+4u*(b))<<8) | \
                                ((32u+4u*(c))<<16) | ((48u+4u*(d))<<24)))
__device__ const unsigned PERM_PK[32] = {
    PK(0,1,2,3), PK(0,1,3,2), PK(0,2,1,3), PK(0,2,3,1), PK(0,3,1,2), PK(0,3,2,1),
    PK(1,0,2,3), PK(1,0,3,2), PK(1,2,0,3), PK(1,2,3,0), PK(1,3,0,2), PK(1,3,2,0),
    PK(2,0,1,3), PK(2,0,3,1), PK(2,1,0,3), PK(2,1,3,0), PK(2,3,0,1), PK(2,3,1,0),
    PK(3,0,1,2), PK(3,0,2,1), PK(3,1,0,2), PK(3,1,2,0), PK(3,2,0,1), PK(3,2,1,0),
    PK(0,1,2,3), PK(0,1,2,3), PK(0,1,2,3), PK(0,1,2,3),
    PK(0,1,2,3), PK(0,1,2,3), PK(0,1,2,3), PK(0,1,2,3)
};

__global__ __launch_bounds__(512) void hsl_partial(
    const float* __restrict__ assign,    // [B,4,12,12]
    const float* __restrict__ cat,       // [B,4]
    const float* __restrict__ alabels,   // [B,4,12,12]
    const float* __restrict__ clabels,   // [B,4]
    float* __restrict__ bsums)           // [nblocks] per-block partial
{
    __shared__ float lred[8];

    const int tid  = (int)threadIdx.x;
    const int wib  = tid >> 6;               // wave in block, 0..7
    const int lane = tid & 63;
    const int b    = (int)blockIdx.x * 8 + wib;

    const float* __restrict__ A = assign  + (size_t)b * 576;
    const float* __restrict__ Y = alabels + (size_t)b * 576;

    // issued early, consumed in the tail
    const unsigned pk = PERM_PK[lane & 31];

    // category BCE table, computed wave-wide concurrently with the main
    // loop: lane (4p+q) [mod 16] holds BCE_log2(cat[q] vs clabels[p]).
    float catv;
    {
        const int gq = lane & 3;
        const int gp = (lane >> 2) & 3;
        const float cq  = cat[(size_t)b * 4 + gq];
        const float cyp = clabels[(size_t)b * 4 + gp];
        const float arg = (cyp != 0.0f) ? cq : 1.0f - cq;
        catv = fmaxf(__log2f(arg), LOG2_CLIP);
    }

    // s[4p+q] += y[p]*(la[q]-lb[q]);  T[q] += lb[q]   (log2 domain)
    float s[16], T[4];
#pragma unroll
    for (int i = 0; i < 16; ++i) s[i] = 0.0f;
#pragma unroll
    for (int i = 0; i < 4; ++i) T[i] = 0.0f;

#pragma unroll
    for (int it = 0; it < 3; ++it) {
        if (it < 2 || lane < 16) {           // e = lane + 64*it < 144
            const int e = lane + it * 64;
            float d[4], y[4];
#pragma unroll
            for (int q = 0; q < 4; ++q) {
                const float a  = A[q * 144 + e];
                const float la = fmaxf(__log2f(a),        LOG2_CLIP);
                const float lb = fmaxf(__log2f(1.0f - a), LOG2_CLIP);
                d[q] = la - lb;
                T[q] += lb;
            }
#pragma unroll
            for (int p = 0; p < 4; ++p) y[p] = Y[p * 144 + e];
#pragma unroll
            for (int p = 0; p < 4; ++p)
#pragma unroll
                for (int q = 0; q < 4; ++q)
                    s[p * 4 + q] = fmaf(y[p], d[q], s[p * 4 + q]);
        }
    }
#pragma unroll
    for (int i = 0; i < 16; ++i) s[i] += T[i & 3];

    // ---- reduce-scatter: stage32/16 via permlane swaps (VALU), stage 8/4
    // via ds_swizzle keep/send, stages 2/1 via DPP. ----
    float t[8];
#pragma unroll
    for (int i = 0; i < 8; ++i) t[i] = pl32_add(s[i], s[i + 8]);
    float u[4];
#pragma unroll
    for (int i = 0; i < 4; ++i) u[i] = pl16_add(t[i], t[i + 4]);

    const bool h8 = (lane & 8) != 0;
    const bool h4 = (lane & 4) != 0;
    float w[2];
#pragma unroll
    for (int i = 0; i < 2; ++i) {
        const float keep = h8 ? u[i + 2] : u[i];
        const float send = h8 ? u[i]     : u[i + 2];
        w[i] = keep + __shfl_xor(send, 8, 64);
    }
    float x;
    {
        const float keep = h4 ? w[1] : w[0];
        const float send = h4 ? w[0] : w[1];
        x = keep + __shfl_xor(send, 4, 64);
    }
    x += dpp_x2(x);
    x += dpp_x1(x);
    // lane l: x == total s[l >> 2]

    // ---- perm-parallel scoring: lane j < 24 evaluates perm j ----
    const int a0 = (int)( pk        & 0xFFu);
    const int a1 = (int)((pk >> 8)  & 0xFFu);
    const int a2 = (int)((pk >> 16) & 0xFFu);
    const int a3 = (int)( pk >> 24        );
    const float v0 = __shfl(x, a0, 64);
    const float v1 = __shfl(x, a1, 64);
    const float v2 = __shfl(x, a2, 64);
    const float v3 = __shfl(x, a3, 64);
    float score = (v0 + v1) + (v2 + v3);
    if (lane >= 24) score = -__builtin_huge_valf();

    // max over the 32-lane group: 3 swizzle + 2 DPP, score only
    float smax = score;
    smax = fmaxf(smax, __shfl_xor(smax, 16, 64));
    smax = fmaxf(smax, __shfl_xor(smax, 8, 64));
    smax = fmaxf(smax, __shfl_xor(smax, 4, 64));
    smax = fmaxf(smax, dpp_x2(smax));
    smax = fmaxf(smax, dpp_x1(smax));

    // winner lane = lowest lane holding the max (== numpy argmin first-index
    // tie-break; lexicographic perm order == lane order).
    const unsigned long long bal = __ballot(score == smax);
    const int win = (int)__builtin_ctzll(bal);
    const unsigned pkw = (unsigned)__builtin_amdgcn_readlane((int)pk, win);

    // category sum for the winning perm: 4 wave-uniform readlanes on catv
    const int c0 = (int)((pkw >> 2)  & 0x0Fu);
    const int c1 = (int)((pkw >> 10) & 0x0Fu);
    const int c2 = (int)((pkw >> 18) & 0x0Fu);
    const int c3 = (int)((pkw >> 26) & 0x0Fu);
    const float g0 = __int_as_float(__builtin_amdgcn_readlane(__float_as_int(catv), c0));
    const float g1 = __int_as_float(__builtin_amdgcn_readlane(__float_as_int(catv), c1));
    const float g2 = __int_as_float(__builtin_amdgcn_readlane(__float_as_int(catv), c2));
    const float g3 = __int_as_float(__builtin_amdgcn_readlane(__float_as_int(catv), c3));
    const float csum = (g0 + g1) + (g2 + g3);

    if (lane == 0) {
        // per-batch contribution (>= 0): -ln2 * (smax/576 + csum/8)
        lred[wib] = -LN2F * (smax * (1.0f / 576.0f) + 0.125f * csum);
    }
    __syncthreads();

    if (tid == 0) {
        bsums[blockIdx.x] = ((lred[0] + lred[1]) + (lred[2] + lred[3]))
                          + ((lred[4] + lred[5]) + (lred[6] + lred[7]));
    }
}

__global__ __launch_bounds__(64) void hsl_reduce(
    const float* __restrict__ bsums,     // [n] per-block partials
    float* __restrict__ out,
    int n, int B)
{
    const int lane = (int)threadIdx.x;   // one 64-lane wave

    const float4* __restrict__ v4 = (const float4*)bsums;
    const int n4 = n >> 2;               // 256 for n=1024
    double d = 0.0;
    for (int i = lane; i < n4; i += 64) {
        const float4 v = v4[i];
        d += (double)((v.x + v.y) + (v.z + v.w));
    }

    // fp64 butterfly across the wave, fixed order, no LDS/barriers
#pragma unroll
    for (int m = 32; m >= 1; m >>= 1)
        d += __shfl_xor(d, m, 64);

    if (lane == 0) out[0] = (float)(d / (double)B);
}

extern "C" void kernel_launch(void* const* d_in, const int* in_sizes, int n_in,
                              void* d_out, int out_size, void* d_ws, size_t ws_size,
                              hipStream_t stream) {
    const float* assign  = (const float*)d_in[0];
    const float* cat     = (const float*)d_in[1];
    const float* alabels = (const float*)d_in[2];
    const float* clabels = (const float*)d_in[3];
    float* out = (float*)d_out;

    const int B = in_sizes[0] / 576;  // 8192
    float* bsums = (float*)d_ws;

    const int nblocks = B / 8;        // 8 batches per 512-thread block
    hipLaunchKernelGGL(hsl_partial, dim3(nblocks), dim3(512), 0, stream,
                       assign, cat, alabels, clabels, bsums);
    hipLaunchKernelGGL(hsl_reduce, dim3(1), dim3(64), 0, stream,
                       bsums, out, nblocks, B);
}

// Round 12
// 13.912 us; speedup vs baseline: 1.0311x; 1.0311x over previous
//
#include <hip/hip_runtime.h>
#include <math.h>

// HybridSymmetricLoss: B=8192, P=4, M=12, 24 perms.
// pairS[p][q] = sum_{i,j} (y[p] ? log a[q] : log1p(-a[q]))  (negated BCE)
// best perm = argmax_sigma sum_p pairS[p][sigma(p)]; category BCE via sigma.
// kernel1: TWO batches per 64-lane wave (sequential r10-style main loops,
//   each batch fully coalesced), MERGED tail: 6-stage reduce-scatter
//   (batch selected by lane bit5 via permlane32_swap, g-bits by 16/8/4/2,
//   completion at mask 1) -> lane l holds SB[l>>5][(l>>1)&15]; both
//   batches' 24 perms scored in parallel (lanes 0-23 / 32-55); one ballot,
//   per-half ctz argmin; catv per half. 4 waves/block, 1024 blocks.
// kernel2: r10's barrier-minimal single-block reduce (1024 partials).

#define LOG2_CLIP (-144.26950408889634f)   // -100 / ln(2)
#define LN2F      (0.6931471805599453f)

typedef int v2i __attribute__((ext_vector_type(2)));

// lane<32: a[lane]+a[lane^32] ; lane>=32: b[lane]+b[lane^32]   [HW-validated r10]
__device__ __forceinline__ float pl32_add(float a, float b) {
    v2i r = __builtin_amdgcn_permlane32_swap(__float_as_int(a),
                                             __float_as_int(b), false, false);
    return __int_as_float(r[0]) + __int_as_float(r[1]);
}
// (lane&16)==0: a[lane]+a[lane^16] ; else: b[lane]+b[lane^16]  [HW-validated r10]
__device__ __forceinline__ float pl16_add(float a, float b) {
    v2i r = __builtin_amdgcn_permlane16_swap(__float_as_int(a),
                                             __float_as_int(b), false, false);
    return __int_as_float(r[0]) + __int_as_float(r[1]);
}
// DPP quad_perm xor-1 (pure VALU)
__device__ __forceinline__ float dpp_x1(float x) {
    return __int_as_float(__builtin_amdgcn_update_dpp(
        0, __float_as_int(x), 0xB1, 0xF, 0xF, false));
}
__device__ __forceinline__ float dpp_x2(float x) {
    return __int_as_float(__builtin_amdgcn_update_dpp(
        0, __float_as_int(x), 0x4E, 0xF, 0xF, false));
}

// perm table, lexicographic. byte p = 16*p + 4*sigma(p);
// x-gather lane = byte>>1 (pair base 2g); catv lane = byte>>2 (= g).
#define PK(a,b,c,d) ((unsigned)((4u*(a)) | ((16u+4u*(b))<<8) | \
                                ((32u+4u*(c))<<16) | ((48u+4u*(d))<<24)))
__device__ const unsigned PERM_PK[32] = {
    PK(0,1,2,3), PK(0,1,3,2), PK(0,2,1,3), PK(0,2,3,1), PK(0,3,1,2), PK(0,3,2,1),
    PK(1,0,2,3), PK(1,0,3,2), PK(1,2,0,3), PK(1,2,3,0), PK(1,3,0,2), PK(1,3,2,0),
    PK(2,0,1,3), PK(2,0,3,1), PK(2,1,0,3), PK(2,1,3,0), PK(2,3,0,1), PK(2,3,1,0),
    PK(3,0,1,2), PK(3,0,2,1), PK(3,1,0,2), PK(3,1,2,0), PK(3,2,0,1), PK(3,2,1,0),
    PK(0,1,2,3), PK(0,1,2,3), PK(0,1,2,3), PK(0,1,2,3),
    PK(0,1,2,3), PK(0,1,2,3), PK(0,1,2,3), PK(0,1,2,3)
};

// r10 main loop for one batch, accumulating into sacc[16] (T folded).
#define MAIN_LOOP(Aptr, Yptr, sacc)                                           \
    {                                                                         \
        float T[4];                                                           \
        _Pragma("unroll")                                                     \
        for (int i = 0; i < 4; ++i) T[i] = 0.0f;                              \
        _Pragma("unroll")                                                     \
        for (int it = 0; it < 3; ++it) {                                      \
            if (it < 2 || lane < 16) {                                        \
                const int e = lane + it * 64;                                 \
                float d[4], y[4];                                             \
                _Pragma("unroll")                                             \
                for (int q = 0; q < 4; ++q) {                                 \
                    const float a  = (Aptr)[q * 144 + e];                     \
                    const float la = fmaxf(__log2f(a),        LOG2_CLIP);     \
                    const float lb = fmaxf(__log2f(1.0f - a), LOG2_CLIP);     \
                    d[q] = la - lb;                                           \
                    T[q] += lb;                                               \
                }                                                             \
                _Pragma("unroll")                                             \
                for (int p = 0; p < 4; ++p) y[p] = (Yptr)[p * 144 + e];       \
                _Pragma("unroll")                                             \
                for (int p = 0; p < 4; ++p)                                   \
                    _Pragma("unroll")                                         \
                    for (int q = 0; q < 4; ++q)                               \
                        (sacc)[p * 4 + q] = fmaf(y[p], d[q], (sacc)[p * 4 + q]); \
            }                                                                 \
        }                                                                     \
        _Pragma("unroll")                                                     \
        for (int i = 0; i < 16; ++i) (sacc)[i] += T[i & 3];                   \
    }

__global__ __launch_bounds__(256) void hsl_partial(
    const float* __restrict__ assign,    // [B,4,12,12]
    const float* __restrict__ cat,       // [B,4]
    const float* __restrict__ alabels,   // [B,4,12,12]
    const float* __restrict__ clabels,   // [B,4]
    float* __restrict__ bsums)           // [nblocks] per-block partial
{
    __shared__ float lred[4];

    const int tid  = (int)threadIdx.x;
    const int wib  = tid >> 6;               // wave in block, 0..3
    const int lane = tid & 63;
    const int base = ((int)blockIdx.x * 4 + wib) * 2;   // batches base, base+1

    const float* __restrict__ A0 = assign  + (size_t)base * 576;
    const float* __restrict__ Y0 = alabels + (size_t)base * 576;
    const float* __restrict__ A1 = A0 + 576;
    const float* __restrict__ Y1 = Y0 + 576;

    const unsigned pk = PERM_PK[lane & 31];

    // category BCE table, per half: lane l serves batch (l>>5), entry
    // g' = l&15 (dup on bit4): gq = l&3, gp = (l>>2)&3.
    float catv;
    {
        const int bb  = base + (lane >> 5);
        const float cq  = cat[(size_t)bb * 4 + (lane & 3)];
        const float cyp = clabels[(size_t)bb * 4 + ((lane >> 2) & 3)];
        const float arg = (cyp != 0.0f) ? cq : 1.0f - cq;
        catv = fmaxf(__log2f(arg), LOG2_CLIP);
    }

    // two independent main loops (ILP: batch1 loads overlap batch0 compute)
    float s0[16], s1[16];
#pragma unroll
    for (int i = 0; i < 16; ++i) { s0[i] = 0.0f; s1[i] = 0.0f; }
    MAIN_LOOP(A0, Y0, s0)
    MAIN_LOOP(A1, Y1, s1)

    // ---- merged reduce-scatter: 5 selection stages + 1 completion.
    // After: lane l holds total SB[l>>5][(l>>1)&15]. ----
    float m[16];
#pragma unroll
    for (int i = 0; i < 16; ++i) m[i] = pl32_add(s0[i], s1[i]);   // bit5: batch
    float u[8];
#pragma unroll
    for (int i = 0; i < 8; ++i) u[i] = pl16_add(m[i], m[i + 8]);  // bit4: g-bit3

    const bool h8 = (lane & 8) != 0;
    const bool h4 = (lane & 4) != 0;
    const bool h2 = (lane & 2) != 0;
    float w[4];
#pragma unroll
    for (int i = 0; i < 4; ++i) {                                  // bit3: g-bit2
        const float keep = h8 ? u[i + 4] : u[i];
        const float send = h8 ? u[i]     : u[i + 4];
        w[i] = keep + __shfl_xor(send, 8, 64);
    }
    float v[2];
#pragma unroll
    for (int i = 0; i < 2; ++i) {                                  // bit2: g-bit1
        const float keep = h4 ? w[i + 2] : w[i];
        const float send = h4 ? w[i]     : w[i + 2];
        v[i] = keep + __shfl_xor(send, 4, 64);
    }
    float x;
    {                                                              // bit1: g-bit0
        const float keep = h2 ? v[1] : v[0];
        const float send = h2 ? v[0] : v[1];
        x = keep + __shfl_xor(send, 2, 64);
    }
    x += dpp_x1(x);                                                // completion

    // ---- perm scoring, both batches in parallel: lane j<24 -> b0 perm j,
    // lane 32+j -> b1 perm j. gather lane = (byte>>1) | (lane&32). ----
    const int hb = (int)(lane & 32);
    const int a0 = (int)((pk >>  1) & 0x7Fu) | hb;
    const int a1 = (int)((pk >>  9) & 0x7Fu) | hb;
    const int a2 = (int)((pk >> 17) & 0x7Fu) | hb;
    const int a3 = (int)((pk >> 25) & 0x7Fu) | hb;
    const float v0 = __shfl(x, a0, 64);
    const float v1 = __shfl(x, a1, 64);
    const float v2 = __shfl(x, a2, 64);
    const float v3 = __shfl(x, a3, 64);
    float score = (v0 + v1) + (v2 + v3);
    if ((lane & 31) >= 24) score = -__builtin_huge_valf();

    // max within each 32-half (3 swizzle + 2 DPP)
    float smax = score;
    smax = fmaxf(smax, __shfl_xor(smax, 16, 64));
    smax = fmaxf(smax, __shfl_xor(smax, 8, 64));
    smax = fmaxf(smax, __shfl_xor(smax, 4, 64));
    smax = fmaxf(smax, dpp_x2(smax));
    smax = fmaxf(smax, dpp_x1(smax));

    // per-half argmin (lowest lane == lexicographic first == numpy argmin)
    const unsigned long long bal = __ballot(score == smax);
    const int win0 = (int)__builtin_ctzll(bal & 0xFFFFFFFFULL);
    const int win1 = 32 + (int)__builtin_ctzll(bal >> 32);
    const unsigned pkw0 = (unsigned)__builtin_amdgcn_readlane((int)pk, win0);
    const unsigned pkw1 = (unsigned)__builtin_amdgcn_readlane((int)pk, win1);
    const float sm0 = __int_as_float(__builtin_amdgcn_readlane(__float_as_int(smax), 0));
    const float sm1 = __int_as_float(__builtin_amdgcn_readlane(__float_as_int(smax), 32));

    // category sums: catv entry g' on lane g' (b0) / 32+g' (b1)
#define CATR(pkw, off, sh) __int_as_float(__builtin_amdgcn_readlane( \
        __float_as_int(catv), (int)(((pkw) >> (sh)) & 0x0Fu) + (off)))
    const float csum0 = (CATR(pkw0, 0, 2)  + CATR(pkw0, 0, 10))
                      + (CATR(pkw0, 0, 18) + CATR(pkw0, 0, 26));
    const float csum1 = (CATR(pkw1, 32, 2)  + CATR(pkw1, 32, 10))
                      + (CATR(pkw1, 32, 18) + CATR(pkw1, 32, 26));
#undef CATR

    if (lane == 0) {
        // two batches' contributions (>= 0): -ln2 * (smax/576 + csum/8)
        lred[wib] = -LN2F * ((sm0 + sm1) * (1.0f / 576.0f)
                             + 0.125f * (csum0 + csum1));
    }
    __syncthreads();

    if (tid == 0) {
        bsums[blockIdx.x] = (lred[0] + lred[1]) + (lred[2] + lred[3]);
    }
}

__global__ __launch_bounds__(256) void hsl_reduce(
    const float* __restrict__ bsums,     // [n] per-block partials
    float* __restrict__ out,
    int n, int B)
{
    __shared__ double sw[4];
    const int tid  = (int)threadIdx.x;
    const int wid  = tid >> 6;
    const int lane = tid & 63;

    const float4* __restrict__ v4 = (const float4*)bsums;
    const int n4 = n >> 2;               // 256 for n=1024
    double d = 0.0;
    for (int i = tid; i < n4; i += 256) {
        const float4 v = v4[i];
        d += (double)((v.x + v.y) + (v.z + v.w));
    }

#pragma unroll
    for (int m2 = 32; m2 >= 1; m2 >>= 1)
        d += __shfl_xor(d, m2, 64);

    if (lane == 0) sw[wid] = d;
    __syncthreads();

    if (tid == 0) {
        const double t = (sw[0] + sw[1]) + (sw[2] + sw[3]);
        out[0] = (float)(t / (double)B);
    }
}

extern "C" void kernel_launch(void* const* d_in, const int* in_sizes, int n_in,
                              void* d_out, int out_size, void* d_ws, size_t ws_size,
                              hipStream_t stream) {
    const float* assign  = (const float*)d_in[0];
    const float* cat     = (const float*)d_in[1];
    const float* alabels = (const float*)d_in[2];
    const float* clabels = (const float*)d_in[3];
    float* out = (float*)d_out;

    const int B = in_sizes[0] / 576;  // 8192
    float* bsums = (float*)d_ws;

    const int nblocks = B / 8;        // 8 batches per block (4 waves x 2)
    hipLaunchKernelGGL(hsl_partial, dim3(nblocks), dim3(256), 0, stream,
                       assign, cat, alabels, clabels, bsums);
    hipLaunchKernelGGL(hsl_reduce, dim3(1), dim3(256), 0, stream,
                       bsums, out, nblocks, B);
}

// Round 13
// 13.802 us; speedup vs baseline: 1.0393x; 1.0079x over previous
//
#include <hip/hip_runtime.h>
#include <math.h>

// HybridSymmetricLoss: B=8192, P=4, M=12, 24 perms.
// pairS[p][q] = sum_{i,j} (y[p] ? log a[q] : log1p(-a[q]))  (negated BCE)
// best perm = argmax_sigma sum_p pairS[p][sigma(p)]; category BCE via sigma.
// kernel1: 1 batch per 64-lane wave, 4 waves/block, 2048 blocks (measured-
//   best r10 structure). Tail with minimal DS-ops: permlane32/16_swap +
//   DPP quad_perm; argmax via ballot+ctz (first-index tie-break == numpy
//   argmin); category BCE precomputed on 16 lanes, gathered via readlane.
// kernel2: barrier-minimal single-block reduce, fp64, fixed order.
//
// Structural floor (measured over r1-r12): k1 ~5-6us = mandatory 37.7MB
// input reads (half HBM / half L3) + ramp; k2 ~2us single-block latency;
// ~5-6us graph/launch fixed. Fusion via device-scope atomics/fences costs
// more than it saves on gfx950 (r4: ~27ns per serialized fence+RMW).

#define LOG2_CLIP (-144.26950408889634f)   // -100 / ln(2)
#define LN2F      (0.6931471805599453f)

typedef int v2i __attribute__((ext_vector_type(2)));

// lane<32: a[lane]+a[lane^32] ; lane>=32: b[lane]+b[lane^32]
__device__ __forceinline__ float pl32_add(float a, float b) {
    v2i r = __builtin_amdgcn_permlane32_swap(__float_as_int(a),
                                             __float_as_int(b), false, false);
    return __int_as_float(r[0]) + __int_as_float(r[1]);
}
// (lane&16)==0: a[lane]+a[lane^16] ; else: b[lane]+b[lane^16]
__device__ __forceinline__ float pl16_add(float a, float b) {
    v2i r = __builtin_amdgcn_permlane16_swap(__float_as_int(a),
                                             __float_as_int(b), false, false);
    return __int_as_float(r[0]) + __int_as_float(r[1]);
}
// DPP quad_perm xor-1 / xor-2 (pure VALU, no LDS pipe)
__device__ __forceinline__ float dpp_x1(float x) {
    return __int_as_float(__builtin_amdgcn_update_dpp(
        0, __float_as_int(x), 0xB1, 0xF, 0xF, false));
}
__device__ __forceinline__ float dpp_x2(float x) {
    return __int_as_float(__builtin_amdgcn_update_dpp(
        0, __float_as_int(x), 0x4E, 0xF, 0xF, false));
}

// perm table, lexicographic. byte p = 16*p + 4*sigma(p) = x-gather lane;
// byte>>2 = 4*p + sigma(p) = catv lane.
#define PK(a,b,c,d) ((unsigned)((4u*(a)) | ((16u+4u*(b))<<8) | \
                                ((32u+4u*(c))<<16) | ((48u+4u*(d))<<24)))
__device__ const unsigned PERM_PK[32] = {
    PK(0,1,2,3), PK(0,1,3,2), PK(0,2,1,3), PK(0,2,3,1), PK(0,3,1,2), PK(0,3,2,1),
    PK(1,0,2,3), PK(1,0,3,2), PK(1,2,0,3), PK(1,2,3,0), PK(1,3,0,2), PK(1,3,2,0),
    PK(2,0,1,3), PK(2,0,3,1), PK(2,1,0,3), PK(2,1,3,0), PK(2,3,0,1), PK(2,3,1,0),
    PK(3,0,1,2), PK(3,0,2,1), PK(3,1,0,2), PK(3,1,2,0), PK(3,2,0,1), PK(3,2,1,0),
    PK(0,1,2,3), PK(0,1,2,3), PK(0,1,2,3), PK(0,1,2,3),
    PK(0,1,2,3), PK(0,1,2,3), PK(0,1,2,3), PK(0,1,2,3)
};

__global__ __launch_bounds__(256) void hsl_partial(
    const float* __restrict__ assign,    // [B,4,12,12]
    const float* __restrict__ cat,       // [B,4]
    const float* __restrict__ alabels,   // [B,4,12,12]
    const float* __restrict__ clabels,   // [B,4]
    float* __restrict__ bsums)           // [nblocks] per-block partial
{
    __shared__ float lred[4];

    const int tid  = (int)threadIdx.x;
    const int wib  = tid >> 6;               // wave in block, 0..3
    const int lane = tid & 63;
    const int b    = (int)blockIdx.x * 4 + wib;

    const float* __restrict__ A = assign  + (size_t)b * 576;
    const float* __restrict__ Y = alabels + (size_t)b * 576;

    // issued early, consumed in the tail
    const unsigned pk = PERM_PK[lane & 31];

    // category BCE table, computed wave-wide concurrently with the main
    // loop: lane (4p+q) [mod 16] holds BCE_log2(cat[q] vs clabels[p]).
    float catv;
    {
        const int gq = lane & 3;
        const int gp = (lane >> 2) & 3;
        const float cq  = cat[(size_t)b * 4 + gq];
        const float cyp = clabels[(size_t)b * 4 + gp];
        const float arg = (cyp != 0.0f) ? cq : 1.0f - cq;
        catv = fmaxf(__log2f(arg), LOG2_CLIP);
    }

    // s[4p+q] += y[p]*(la[q]-lb[q]);  T[q] += lb[q]   (log2 domain)
    float s[16], T[4];
#pragma unroll
    for (int i = 0; i < 16; ++i) s[i] = 0.0f;
#pragma unroll
    for (int i = 0; i < 4; ++i) T[i] = 0.0f;

#pragma unroll
    for (int it = 0; it < 3; ++it) {
        if (it < 2 || lane < 16) {           // e = lane + 64*it < 144
            const int e = lane + it * 64;
            float d[4], y[4];
#pragma unroll
            for (int q = 0; q < 4; ++q) {
                const float a  = A[q * 144 + e];
                const float la = fmaxf(__log2f(a),        LOG2_CLIP);
                const float lb = fmaxf(__log2f(1.0f - a), LOG2_CLIP);
                d[q] = la - lb;
                T[q] += lb;
            }
#pragma unroll
            for (int p = 0; p < 4; ++p) y[p] = Y[p * 144 + e];
#pragma unroll
            for (int p = 0; p < 4; ++p)
#pragma unroll
                for (int q = 0; q < 4; ++q)
                    s[p * 4 + q] = fmaf(y[p], d[q], s[p * 4 + q]);
        }
    }
#pragma unroll
    for (int i = 0; i < 16; ++i) s[i] += T[i & 3];

    // ---- reduce-scatter: stage32/16 via permlane swaps (VALU), stage 8/4
    // via ds_swizzle keep/send, stages 2/1 via DPP. ----
    float t[8];
#pragma unroll
    for (int i = 0; i < 8; ++i) t[i] = pl32_add(s[i], s[i + 8]);
    float u[4];
#pragma unroll
    for (int i = 0; i < 4; ++i) u[i] = pl16_add(t[i], t[i + 4]);

    const bool h8 = (lane & 8) != 0;
    const bool h4 = (lane & 4) != 0;
    float w[2];
#pragma unroll
    for (int i = 0; i < 2; ++i) {
        const float keep = h8 ? u[i + 2] : u[i];
        const float send = h8 ? u[i]     : u[i + 2];
        w[i] = keep + __shfl_xor(send, 8, 64);
    }
    float x;
    {
        const float keep = h4 ? w[1] : w[0];
        const float send = h4 ? w[0] : w[1];
        x = keep + __shfl_xor(send, 4, 64);
    }
    x += dpp_x2(x);
    x += dpp_x1(x);
    // lane l: x == total s[l >> 2]

    // ---- perm-parallel scoring: lane j < 24 evaluates perm j ----
    const int a0 = (int)( pk        & 0xFFu);
    const int a1 = (int)((pk >> 8)  & 0xFFu);
    const int a2 = (int)((pk >> 16) & 0xFFu);
    const int a3 = (int)( pk >> 24        );
    const float v0 = __shfl(x, a0, 64);
    const float v1 = __shfl(x, a1, 64);
    const float v2 = __shfl(x, a2, 64);
    const float v3 = __shfl(x, a3, 64);
    float score = (v0 + v1) + (v2 + v3);
    if (lane >= 24) score = -__builtin_huge_valf();

    // max over the 32-lane group: 3 swizzle + 2 DPP, score only
    float smax = score;
    smax = fmaxf(smax, __shfl_xor(smax, 16, 64));
    smax = fmaxf(smax, __shfl_xor(smax, 8, 64));
    smax = fmaxf(smax, __shfl_xor(smax, 4, 64));
    smax = fmaxf(smax, dpp_x2(smax));
    smax = fmaxf(smax, dpp_x1(smax));

    // winner lane = lowest lane holding the max (== numpy argmin first-index
    // tie-break; lexicographic perm order == lane order).
    const unsigned long long bal = __ballot(score == smax);
    const int win = (int)__builtin_ctzll(bal);
    const unsigned pkw = (unsigned)__builtin_amdgcn_readlane((int)pk, win);

    // category sum for the winning perm: 4 wave-uniform readlanes on catv
    const int c0 = (int)((pkw >> 2)  & 0x0Fu);
    const int c1 = (int)((pkw >> 10) & 0x0Fu);
    const int c2 = (int)((pkw >> 18) & 0x0Fu);
    const int c3 = (int)((pkw >> 26) & 0x0Fu);
    const float g0 = __int_as_float(__builtin_amdgcn_readlane(__float_as_int(catv), c0));
    const float g1 = __int_as_float(__builtin_amdgcn_readlane(__float_as_int(catv), c1));
    const float g2 = __int_as_float(__builtin_amdgcn_readlane(__float_as_int(catv), c2));
    const float g3 = __int_as_float(__builtin_amdgcn_readlane(__float_as_int(catv), c3));
    const float csum = (g0 + g1) + (g2 + g3);

    if (lane == 0) {
        // per-batch contribution (>= 0): -ln2 * (smax/576 + csum/8)
        lred[wib] = -LN2F * (smax * (1.0f / 576.0f) + 0.125f * csum);
    }
    __syncthreads();

    if (tid == 0) {
        bsums[blockIdx.x] = (lred[0] + lred[1]) + (lred[2] + lred[3]);
    }
}

__global__ __launch_bounds__(256) void hsl_reduce(
    const float* __restrict__ bsums,     // [n] per-block partials
    float* __restrict__ out,
    int n, int B)
{
    __shared__ double sw[4];
    const int tid  = (int)threadIdx.x;
    const int wid  = tid >> 6;
    const int lane = tid & 63;

    const float4* __restrict__ v4 = (const float4*)bsums;
    const int n4 = n >> 2;
    double d = 0.0;
    for (int i = tid; i < n4; i += 256) {
        const float4 v = v4[i];
        d += (double)((v.x + v.y) + (v.z + v.w));
    }

#pragma unroll
    for (int m = 32; m >= 1; m >>= 1)
        d += __shfl_xor(d, m, 64);

    if (lane == 0) sw[wid] = d;
    __syncthreads();

    if (tid == 0) {
        const double t = (sw[0] + sw[1]) + (sw[2] + sw[3]);
        out[0] = (float)(t / (double)B);
    }
}

extern "C" void kernel_launch(void* const* d_in, const int* in_sizes, int n_in,
                              void* d_out, int out_size, void* d_ws, size_t ws_size,
                              hipStream_t stream) {
    const float* assign  = (const float*)d_in[0];
    const float* cat     = (const float*)d_in[1];
    const float* alabels = (const float*)d_in[2];
    const float* clabels = (const float*)d_in[3];
    float* out = (float*)d_out;

    const int B = in_sizes[0] / 576;  // 8192
    float* bsums = (float*)d_ws;

    const int nblocks = B / 4;        // 4 batches per 256-thread block
    hipLaunchKernelGGL(hsl_partial, dim3(nblocks), dim3(256), 0, stream,
                       assign, cat, alabels, clabels, bsums);
    hipLaunchKernelGGL(hsl_reduce, dim3(1), dim3(256), 0, stream,
                       bsums, out, nblocks, B);
}